// Round 2
// baseline (766.667 us; speedup 1.0000x reference)
//
#include <hip/hip_runtime.h>
#include <hip/hip_fp16.h>

// NLSPN deformable propagation, B=4, H=480, W=640, 18 steps.
// Round 2: per-sample descriptors precomputed ONCE (clamped absolute gather
// index + 4 fp16 corner weights with aff_k folded). Per-step kernel is a pure
// gather+FMA: 9 x (idx, w4, two row gathers) + affine epilogue.
// State g = f*conf; step: g' = A*sum_k w.corners + C;  last step: f = acc', C'.

#define HH 480
#define WW 640
#define BB 4
#define HWSZ (HH * WW)        // 307200
#define NPIX (BB * HWSZ)      // 1228800
#define PROP_T 18
#define SLACK 704             // > W+1 floats of slack each side of ping-pong bufs

struct f2u { float x, y; };   // 4-aligned pair load

__device__ __forceinline__ float fast_tanh(float x) {
    x = fminf(fmaxf(x, -15.0f), 15.0f);
    float e = __expf(2.0f * x);
    return __fdividef(e - 1.0f, e + 1.0f);
}

// One-time: per-pixel state init + ac constants + 9 sample descriptors.
__global__ __launch_bounds__(256) void precompute_kernel(
    const float* __restrict__ feat_init,
    const float* __restrict__ guid,
    const float* __restrict__ confidence,
    const float* __restrict__ feat_fix,
    const float* __restrict__ aff_scale,
    float* __restrict__ g0,           // interior base of bufA
    float2* __restrict__ ac_mid,
    float2* __restrict__ ac_last,
    int* __restrict__ idxArr,         // [9][NPIX], absolute (batch folded)
    uint2* __restrict__ wArr) {       // [9][NPIX], {half2(w00,w01), half2(w10,w11)}
    const int x = blockIdx.x * 64 + threadIdx.x;
    const int y = blockIdx.y * 4 + threadIdx.y;
    const int b = blockIdx.z;
    const int q = y * WW + x;
    const int pix = b * HWSZ + q;
    const float* gb = guid + (size_t)b * 24 * HWSZ + q;

    // state init + affine constants
    {
        float ff = feat_fix[pix];
        float m  = (ff > 0.0f) ? 1.0f : 0.0f;
        float km = 1.0f - m;
        float conf = km * confidence[pix] + m;
        float f0   = km * feat_init[pix] + m * ff;
        g0[pix] = f0 * conf;
        ac_mid[pix]  = make_float2(conf * km, conf * m * ff);
        ac_last[pix] = make_float2(km, m * ff);
    }

    // affinity normalization (fixed for all 18 steps)
    const float inv_scale = __fdividef(1.0f, aff_scale[0] + 1e-8f);
    float t[8];
    float ssum = 1e-4f;
#pragma unroll
    for (int j = 0; j < 8; ++j) {
        float v = fast_tanh(gb[(16 + j) * HWSZ]) * inv_scale;
        t[j] = v;
        ssum += fabsf(v);
    }
    ssum = fmaxf(ssum, 1.0f);
    float rs = __fdividef(1.0f, ssum);
    float asum = 0.0f;
#pragma unroll
    for (int j = 0; j < 8; ++j) { t[j] *= rs; asum += t[j]; }
    const float aref = 1.0f - asum;

    const float yf = (float)y, xf = (float)x;
    constexpr int KY[9] = {-1, -1, -1, 0, 0, 0, 1, 1, 1};
    constexpr int KX[9] = {-1, 0, 1, -1, 0, 1, -1, 0, 1};
#pragma unroll
    for (int k = 0; k < 9; ++k) {
        float dy, dx, ak;
        if (k == 4) {
            dy = 0.0f; dx = 0.0f; ak = aref;
        } else {
            const int n = (k < 4) ? k : (k - 1);
            dy = gb[(2 * n) * HWSZ];
            dx = gb[(2 * n + 1) * HWSZ];
            ak = t[n];
        }
        float py = yf + (float)KY[k] + dy;
        float px = xf + (float)KX[k] + dx;
        float y0f = floorf(py), x0f = floorf(px);
        float wy = py - y0f, wx = px - x0f;
        int y0 = (int)y0f, x0 = (int)x0f;
        float vy0 = (y0 >= 0 && y0 < HH) ? 1.0f : 0.0f;
        float vy1 = (y0 >= -1 && y0 < HH - 1) ? 1.0f : 0.0f;
        float vx0 = (x0 >= 0 && x0 < WW) ? 1.0f : 0.0f;
        float vx1 = (x0 >= -1 && x0 < WW - 1) ? 1.0f : 0.0f;
        float omwy = 1.0f - wy, omwx = 1.0f - wx;
        float w00 = omwy * omwx * vy0 * vx0 * ak;
        float w01 = omwy * wx  * vy0 * vx1 * ak;
        float w10 = wy * omwx  * vy1 * vx0 * ak;
        float w11 = wy * wx    * vy1 * vx1 * ak;
        int yc = min(max(y0, -1), HH - 1);
        int xc = min(max(x0, -1), WW - 1);
        int idx = b * HWSZ + yc * WW + xc;   // absolute; slack covers -641..NPIX+641

        idxArr[k * NPIX + pix] = idx;
        __half2 hab = __floats2half2_rn(w00, w01);
        __half2 hcd = __floats2half2_rn(w10, w11);
        uint2 wr;
        wr.x = *reinterpret_cast<unsigned int*>(&hab);
        wr.y = *reinterpret_cast<unsigned int*>(&hcd);
        wArr[k * NPIX + pix] = wr;
    }
}

__global__ __launch_bounds__(256) void step_kernel(
    const float* __restrict__ fin,    // interior base (batch 0 px 0)
    float* __restrict__ fout,         // interior base of output (or d_out)
    const int* __restrict__ idxArr,
    const uint2* __restrict__ wArr,
    const float2* __restrict__ ac) {
    const int pix = blockIdx.x * 256 + threadIdx.x;
    float acc = 0.0f;
#pragma unroll
    for (int k = 0; k < 9; ++k) {
        int idx = idxArr[k * NPIX + pix];
        uint2 wr = wArr[k * NPIX + pix];
        const float* p = fin + idx;
        f2u r0 = *reinterpret_cast<const f2u*>(p);
        f2u r1 = *reinterpret_cast<const f2u*>(p + WW);
        float2 wab = __half22float2(*reinterpret_cast<__half2*>(&wr.x));
        float2 wcd = __half22float2(*reinterpret_cast<__half2*>(&wr.y));
        acc += wab.x * r0.x + wab.y * r0.y + wcd.x * r1.x + wcd.y * r1.y;
    }
    float2 c2 = ac[pix];
    fout[pix] = c2.x * acc + c2.y;
}

extern "C" void kernel_launch(void* const* d_in, const int* in_sizes, int n_in,
                              void* d_out, int out_size, void* d_ws, size_t ws_size,
                              hipStream_t stream) {
    const float* feat_init  = (const float*)d_in[0];
    const float* guidance   = (const float*)d_in[1];
    const float* confidence = (const float*)d_in[2];
    const float* feat_fix   = (const float*)d_in[3];
    const float* aff_scale  = (const float*)d_in[4];

    // ws layout: bufA | bufB | acMid | acLast | idxArr | wArr  (~162 MB, ws ~450 MiB)
    const size_t bufFloats = (size_t)NPIX + 2 * SLACK;
    float* bufA = (float*)d_ws;
    float* bufB = bufA + bufFloats;
    float2* acMid  = (float2*)(bufB + bufFloats);
    float2* acLast = acMid + NPIX;
    int*   idxArr  = (int*)(acLast + NPIX);
    uint2* wArr    = (uint2*)(idxArr + 9 * (size_t)NPIX);
    float* fA = bufA + SLACK;
    float* fB = bufB + SLACK;

    // zero state buffers so weight-0 OOB/slack gathers read finite values
    hipMemsetAsync(bufA, 0, bufFloats * sizeof(float), stream);
    hipMemsetAsync(bufB, 0, bufFloats * sizeof(float), stream);

    {
        dim3 blk(64, 4, 1);
        dim3 grd(WW / 64, HH / 4, BB);
        precompute_kernel<<<grd, blk, 0, stream>>>(
            feat_init, guidance, confidence, feat_fix, aff_scale,
            fA, acMid, acLast, idxArr, wArr);
    }

    for (int t = 0; t < PROP_T; ++t) {
        const float* fin = (t & 1) ? fB : fA;
        float* fout = (t == PROP_T - 1) ? (float*)d_out : ((t & 1) ? fA : fB);
        const float2* ac = (t == PROP_T - 1) ? acLast : acMid;
        step_kernel<<<NPIX / 256, 256, 0, stream>>>(fin, fout, idxArr, wArr, ac);
    }
}